// Round 13
// baseline (161.504 us; speedup 1.0000x reference)
//
#include <hip/hip_runtime.h>
#include <stdint.h>

#define S_LEN 4096
#define D_EMB 1024
#define NH 16
#define DHEAD 64
#define N3 3072

typedef __attribute__((ext_vector_type(8))) short short8;
typedef __attribute__((ext_vector_type(4))) short short4v;
typedef __attribute__((ext_vector_type(4))) float f32x4;

// workspace layout (ushort elements)
#define OFF_XB    0u         // x bf16; reused as chunk-1 attn partial after gemm1
#define OFF_WINT  4194304u   // W_in^T bf16; reused as attn (m,l) after gemm1
#define OFF_WOUTT 7340032u   // W_out^T bf16 (live until gemm2)
#define OFF_Q     8388608u   // q [H][S][64], k [H][S][64], v^T [H][64][S]
#define OFF_ATTN  20971520u  // chunk-0 partial / combined attn out [4096][1024]

// 0.125 (1/sqrt(64)) * log2(e)
#define QSCALE 0.1803368801111204f
#define DEFER_THR 11.0f

__device__ __forceinline__ unsigned short f2bf(float f) {
  unsigned u = __float_as_uint(f);
  unsigned r = u + 0x7FFFu + ((u >> 16) & 1u);
  return (unsigned short)(r >> 16);
}
__device__ __forceinline__ float bf2f(unsigned short b) {
  return __uint_as_float(((unsigned)b) << 16);
}
__device__ __forceinline__ unsigned cvtpk_bf16(float lo, float hi) {
  unsigned r;
  asm("v_cvt_pk_bf16_f32 %0, %1, %2" : "=v"(r) : "v"(lo), "v"(hi));
  return r;
}
__device__ __forceinline__ void gload16(const void* g, void* l) {
  __builtin_amdgcn_global_load_lds((const __attribute__((address_space(1))) void*)g,
                                   (__attribute__((address_space(3))) void*)l, 16, 0, 0);
}

// ---------------- elementwise f32 -> bf16 ----------------
__global__ __launch_bounds__(256) void cvt_bf16_kernel(const float* __restrict__ src,
                                                       ushort* __restrict__ dst, int n) {
  int i = (blockIdx.x * 256 + threadIdx.x) * 4;
  if (i + 3 < n) {
    float4 v = *(const float4*)(src + i);
    ushort4 o;
    o.x = f2bf(v.x); o.y = f2bf(v.y); o.z = f2bf(v.z); o.w = f2bf(v.w);
    *(ushort4*)(dst + i) = o;
  }
}

// ---------------- transpose + cast: src[R][C] f32 -> dst[C][R] bf16 ----------------
__global__ __launch_bounds__(256) void transpose_cvt_kernel(const float* __restrict__ src,
                                                            ushort* __restrict__ dst,
                                                            int R, int C) {
  __shared__ float tile[32][33];
  int tx = threadIdx.x & 31, ty = threadIdx.x >> 5;
  int c0 = blockIdx.x * 32, r0 = blockIdx.y * 32;
#pragma unroll
  for (int i = 0; i < 32; i += 8)
    tile[ty + i][tx] = src[(size_t)(r0 + ty + i) * C + c0 + tx];
  __syncthreads();
#pragma unroll
  for (int i = 0; i < 32; i += 8)
    dst[(size_t)(c0 + ty + i) * R + r0 + tx] = f2bf(tile[tx][ty + i]);
}

// ---------------- GEMM1: 256x256 tile, 8-phase counted-vmcnt pipeline (r12) ----------------
__global__ __launch_bounds__(512, 2) void gemm1_8phase(const ushort* __restrict__ A,
                                                       const ushort* __restrict__ Bt,
                                                       const float* __restrict__ bias,
                                                       ushort* __restrict__ o16) {
  __shared__ ushort L[65536];   // A halves at 0..32767, B halves at 32768..
  const int K = 1024;
  int tid = threadIdx.x, w = tid >> 6, lane = tid & 63;
  int wr = w >> 2, wc = w & 3;
  int l15 = lane & 15, g = lane >> 4;
  int lr = lane >> 3, lc = lane & 7;
  int swcol = (lc ^ lr) * 8;       // pre-swizzled global column slot
  int rxor = (l15 & 7) << 3;       // read-side slot XOR (ushort units)
  int id = blockIdx.y * 12 + blockIdx.x;
  int id2 = (id & 7) * 24 + (id >> 3);
  int bm = (id2 / 12) * 256, bn = (id2 % 12) * 256;

  f32x4 acc[8][4];
#pragma unroll
  for (int m = 0; m < 8; ++m)
#pragma unroll
    for (int n = 0; n < 4; ++n) acc[m][n] = (f32x4){0.f, 0.f, 0.f, 0.f};

  auto stageA = [&](int t, int h) {
#pragma unroll
    for (int r2 = 0; r2 < 2; ++r2)
      gload16(A + (size_t)(bm + h * 128 + r2 * 64 + w * 8 + lr) * K + t * 64 + swcol,
              &L[((t & 1) * 2 + h) * 8192 + r2 * 4096 + w * 512]);
  };
  auto stageB = [&](int t, int h) {
#pragma unroll
    for (int r2 = 0; r2 < 2; ++r2)
      gload16(Bt + (size_t)(bn + h * 128 + r2 * 64 + w * 8 + lr) * K + t * 64 + swcol,
              &L[32768 + ((t & 1) * 2 + h) * 8192 + r2 * 4096 + w * 512]);
  };

  short8 bf[4][2], af[2][2];
  auto readB = [&](int tb) {
    int base = 32768 + (tb * 2 + (wc >> 1)) * 8192 + (wc & 1) * 4096;
#pragma unroll
    for (int n = 0; n < 4; ++n)
#pragma unroll
      for (int ks = 0; ks < 2; ++ks)
        bf[n][ks] = *(const short8*)&L[base + (n * 16 + l15) * 64 + ((ks * 32 + g * 8) ^ rxor)];
  };
  auto readA2 = [&](int tb, int m0) {
    int base = (tb * 2 + wr) * 8192;
#pragma unroll
    for (int mi = 0; mi < 2; ++mi)
#pragma unroll
      for (int ks = 0; ks < 2; ++ks)
        af[mi][ks] = *(const short8*)&L[base + ((m0 + mi) * 16 + l15) * 64 + ((ks * 32 + g * 8) ^ rxor)];
  };
  auto mfma8 = [&](int m0) {
#pragma unroll
    for (int mi = 0; mi < 2; ++mi)
#pragma unroll
      for (int n = 0; n < 4; ++n)
#pragma unroll
        for (int ks = 0; ks < 2; ++ks)
          acc[m0 + mi][n] =
              __builtin_amdgcn_mfma_f32_16x16x32_bf16(af[mi][ks], bf[n][ks], acc[m0 + mi][n], 0, 0, 0);
  };

#define BAR() __builtin_amdgcn_s_barrier()
#define LGK0() asm volatile("s_waitcnt lgkmcnt(0)" ::: "memory")
#define VM4() asm volatile("s_waitcnt vmcnt(4)" ::: "memory")
#define VM0() asm volatile("s_waitcnt vmcnt(0)" ::: "memory")

  stageA(0, 0); stageA(0, 1); stageB(0, 0); stageB(0, 1);
  stageB(1, 0); stageB(1, 1);
  VM4();
  BAR();

  for (int i = 0; i < 8; ++i) {
    int T = 2 * i;
    bool more = (T + 2 < 16);
    readB(0); readA2(0, 0); stageA(T + 1, 0);
    BAR(); LGK0();
    __builtin_amdgcn_s_setprio(1); mfma8(0); __builtin_amdgcn_s_setprio(0);
    BAR();
    readA2(0, 2); stageA(T + 1, 1);
    BAR(); LGK0();
    __builtin_amdgcn_s_setprio(1); mfma8(2); __builtin_amdgcn_s_setprio(0);
    BAR();
    readA2(0, 4); if (more) stageB(T + 2, 0);
    BAR(); LGK0();
    __builtin_amdgcn_s_setprio(1); mfma8(4); __builtin_amdgcn_s_setprio(0);
    BAR();
    readA2(0, 6); if (more) stageB(T + 2, 1);
    BAR(); LGK0();
    __builtin_amdgcn_s_setprio(1); mfma8(6); __builtin_amdgcn_s_setprio(0);
    if (more) VM4(); else VM0();
    BAR();
    readB(1); readA2(1, 0); if (more) stageA(T + 2, 0);
    BAR(); LGK0();
    __builtin_amdgcn_s_setprio(1); mfma8(0); __builtin_amdgcn_s_setprio(0);
    BAR();
    readA2(1, 2); if (more) stageA(T + 2, 1);
    BAR(); LGK0();
    __builtin_amdgcn_s_setprio(1); mfma8(2); __builtin_amdgcn_s_setprio(0);
    BAR();
    readA2(1, 4); if (more) stageB(T + 3, 0);
    BAR(); LGK0();
    __builtin_amdgcn_s_setprio(1); mfma8(4); __builtin_amdgcn_s_setprio(0);
    BAR();
    readA2(1, 6); if (more) stageB(T + 3, 1);
    BAR(); LGK0();
    __builtin_amdgcn_s_setprio(1); mfma8(6); __builtin_amdgcn_s_setprio(0);
    if (more) VM4(); else VM0();
    BAR();
  }
#undef BAR
#undef LGK0
#undef VM4
#undef VM0

#pragma unroll
  for (int m = 0; m < 8; ++m) {
    int rbase = bm + wr * 128 + m * 16 + g * 4;
#pragma unroll
    for (int n = 0; n < 4; ++n) {
      int c = bn + wc * 64 + n * 16 + l15;
      float bv = bias[c];
      int which = c >> 10, cc = c & 1023, hh = cc >> 6, dcol = cc & 63;
      if (which == 2) {
        ushort4 o;
        o.x = f2bf(acc[m][n][0] + bv);
        o.y = f2bf(acc[m][n][1] + bv);
        o.z = f2bf(acc[m][n][2] + bv);
        o.w = f2bf(acc[m][n][3] + bv);
        *(ushort4*)&o16[8388608u + (size_t)hh * (DHEAD * (size_t)S_LEN) +
                        (size_t)dcol * S_LEN + rbase] = o;
      } else {
        float qs = (which == 0) ? QSCALE : 1.0f;
        ushort* dst = o16 + (size_t)which * 4194304u +
                      (size_t)hh * (S_LEN * DHEAD) + dcol;
#pragma unroll
        for (int j = 0; j < 4; ++j)
          dst[(size_t)(rbase + j) * DHEAD] = f2bf((acc[m][n][j] + bv) * qs);
      }
    }
  }
}

// ---------------- GEMM2: 128x128 tile, 512 threads (8 waves, 2 waves/SIMD) ----------------
#define BK 64

__global__ __launch_bounds__(512) void gemm2_kernel(const ushort* __restrict__ A,
                                                    const ushort* __restrict__ Bt,
                                                    const float* __restrict__ bias,
                                                    float* __restrict__ o32,
                                                    int N, int K) {
  __shared__ ushort As[128 * 64];
  __shared__ ushort Bs[128 * 64];
  int tid = threadIdx.x, w = tid >> 6, lane = tid & 63;
  int wr = w >> 2, wc = w & 3;           // 2M x 4N waves, per-wave 64x32
  int l15 = lane & 15, g = lane >> 4;
  int lr = lane >> 3, lc = lane & 7;
  int gx = gridDim.x;
  int id = blockIdx.y * gx + blockIdx.x;
  int q8 = (gx * gridDim.y) >> 3;
  int id2 = (id & 7) * q8 + (id >> 3);
  int bm = (id2 / gx) * 128, bn = (id2 % gx) * 128;
  f32x4 acc[4][2];
#pragma unroll
  for (int m = 0; m < 4; ++m)
#pragma unroll
    for (int n = 0; n < 2; ++n) acc[m][n] = (f32x4){0.f, 0.f, 0.f, 0.f};

  for (int k0 = 0; k0 < K; k0 += BK) {
    __syncthreads();
#pragma unroll
    for (int i = 0; i < 2; ++i) {
      int row = i * 64 + w * 8 + lr;
      gload16(A + (size_t)(bm + row) * K + k0 + lc * 8, &As[i * 4096 + w * 512]);
      gload16(Bt + (size_t)(bn + row) * K + k0 + lc * 8, &Bs[i * 4096 + w * 512]);
    }
    __syncthreads();
    short8 a[4][2], b[2][2];
#pragma unroll
    for (int m = 0; m < 4; ++m)
#pragma unroll
      for (int t = 0; t < 2; ++t)
        a[m][t] = *(const short8*)&As[(wr * 64 + m * 16 + l15) * 64 + t * 32 + g * 8];
#pragma unroll
    for (int n = 0; n < 2; ++n)
#pragma unroll
      for (int t = 0; t < 2; ++t)
        b[n][t] = *(const short8*)&Bs[(wc * 32 + n * 16 + l15) * 64 + t * 32 + g * 8];
#pragma unroll
    for (int m = 0; m < 4; ++m)
#pragma unroll
      for (int n = 0; n < 2; ++n)
#pragma unroll
        for (int t = 0; t < 2; ++t)
          acc[m][n] = __builtin_amdgcn_mfma_f32_16x16x32_bf16(a[m][t], b[n][t], acc[m][n], 0, 0, 0);
  }

#pragma unroll
  for (int m = 0; m < 4; ++m) {
    int rbase = bm + wr * 64 + m * 16 + g * 4;
#pragma unroll
    for (int n = 0; n < 2; ++n) {
      int c = bn + wc * 32 + n * 16 + l15;
      float bv = bias[c];
#pragma unroll
      for (int j = 0; j < 4; ++j)
        o32[(size_t)(rbase + j) * N + c] = acc[m][n][j] + bv;
    }
  }
}

// ---------------- causal flash attention, QBLK=256, split-KV x2 ----------------
// Q (pre-scaled, log2 units), K: [H][S][64].  Vt: [H][64][S].
// 8 waves x 32 q-rows: each LDS fragment read feeds 2 MFMAs (DS traffic per
// unit work halved). KVBLK=64, XOR-swizzled dbuf LDS, ONE barrier/tile.
// Grid 512 x 512thr (2 blocks/CU, 16 waves/CU): bid<256 -> (h, qt=15-(bid>>4),
// c=0); else (h, qt=(r>>4), c=1). Round-robin pairs (qt,c0)+(15-qt,c1) -> 34
// tile-units per CU, uniform. Partials + (m,l) out; combine merges.
__global__ __launch_bounds__(512) void attn_kernel(const ushort* __restrict__ Q,
                                                   const ushort* __restrict__ Kg,
                                                   const ushort* __restrict__ Vtg,
                                                   ushort* __restrict__ P0,
                                                   ushort* __restrict__ P1,
                                                   float2* __restrict__ ml) {
  __shared__ ushort Ks[2][64 * 64];
  __shared__ ushort Vs[2][64 * 64];
  int bid = blockIdx.x;
  int c, h, qt;
  if (bid < 256) { c = 0; h = bid & 15; qt = 15 - (bid >> 4); }
  else { int r = bid - 256; c = 1; h = r & 15; qt = r >> 4; }
  int q0 = qt * 256;
  int tid = threadIdx.x, w = tid >> 6, lane = tid & 63;
  int l15 = lane & 15, g = lane >> 4;
  const ushort* qh = Q + (size_t)h * (S_LEN * DHEAD);
  const ushort* kh = Kg + (size_t)h * (S_LEN * DHEAD);
  const ushort* vh = Vtg + (size_t)h * (DHEAD * (size_t)S_LEN);
  ushort* Pc = c ? P1 : P0;
  int sr = tid >> 3;           // 0..63 staging row
  int scc = (tid & 7) * 8;     // 16B per thread
  int wo = sr * 64 + (((scc * 2) ^ ((sr & 7) << 4)) >> 1);
  int kxor = (l15 & 7) << 4;
  int koff0 = ((g * 16) ^ kxor) >> 1;
  int koff1 = ((64 + g * 16) ^ kxor) >> 1;
  int voff[4];
#pragma unroll
  for (int ct = 0; ct < 4; ++ct) voff[ct] = ((ct * 32 + g * 8) ^ kxor) >> 1;

  int qrow0 = q0 + w * 32 + l15;
  int qrow1 = qrow0 + 16;
  short8 aq0[2], aq1[2];
#pragma unroll
  for (int t = 0; t < 2; ++t) {
    aq0[t] = *(const short8*)&qh[(size_t)qrow0 * DHEAD + t * 32 + g * 8];
    aq1[t] = *(const short8*)&qh[(size_t)qrow1 * DHEAD + t * 32 + g * 8];
  }

  f32x4 acc_o0[4], acc_o1[4];
#pragma unroll
  for (int dt = 0; dt < 4; ++dt) {
    acc_o0[dt] = (f32x4){0.f, 0.f, 0.f, 0.f};
    acc_o1[dt] = (f32x4){0.f, 0.f, 0.f, 0.f};
  }
  float m0 = -1e30f, l0 = 0.f, m1 = -1e30f, l1 = 0.f;
  int last = 4 * qt + 3;       // chunk c: it = c, c+2, ..., <= last (>= 2 tiles)

  // prologue: stage tile c (swizzled); prefetch tile c+2 into regs
  {
    int kv0 = c * 64;
    short8 ka = *(const short8*)&kh[(size_t)(kv0 + sr) * DHEAD + scc];
    short8 va = *(const short8*)&vh[(size_t)sr * S_LEN + kv0 + scc];
    *(short8*)&Ks[0][wo] = ka;
    *(short8*)&Vs[0][wo] = va;
  }
  short8 nk, nv;
  {
    int kv2 = (c + 2) * 64;    // c+2 <= last always (last >= 3)
    nk = *(const short8*)&kh[(size_t)(kv2 + sr) * DHEAD + scc];
    nv = *(const short8*)&vh[(size_t)sr * S_LEN + kv2 + scc];
  }
  __syncthreads();
  int cur = 0;

  for (int it = c; it <= last; it += 2) {
    int kv0 = it * 64;
    bool more = (it + 2 <= last);
    const ushort* Kc = Ks[cur];
    const ushort* Vc = Vs[cur];

    // swapped QK^T dual: accX[ct][j] = S^T[key=kv0+ct*16+g*4+j][qrowX]
    f32x4 accs0[4], accs1[4];
#pragma unroll
    for (int ct = 0; ct < 4; ++ct) {
      accs0[ct] = (f32x4){0.f, 0.f, 0.f, 0.f};
      accs1[ct] = (f32x4){0.f, 0.f, 0.f, 0.f};
    }
    __builtin_amdgcn_s_setprio(1);
#pragma unroll
    for (int ct = 0; ct < 4; ++ct) {
      int rb = (ct * 16 + l15) * 64;
      short8 kf0 = *(const short8*)&Kc[rb + koff0];
      short8 kf1 = *(const short8*)&Kc[rb + koff1];
      accs0[ct] = __builtin_amdgcn_mfma_f32_16x16x32_bf16(kf0, aq0[0], accs0[ct], 0, 0, 0);
      accs1[ct] = __builtin_amdgcn_mfma_f32_16x16x32_bf16(kf0, aq1[0], accs1[ct], 0, 0, 0);
      accs0[ct] = __builtin_amdgcn_mfma_f32_16x16x32_bf16(kf1, aq0[1], accs0[ct], 0, 0, 0);
      accs1[ct] = __builtin_amdgcn_mfma_f32_16x16x32_bf16(kf1, aq1[1], accs1[ct], 0, 0, 0);
    }
    __builtin_amdgcn_s_setprio(0);

    if (it >= 4 * qt) {  // diagonal band: causal mask
#pragma unroll
      for (int ct = 0; ct < 4; ++ct) {
        int kbase = kv0 + ct * 16 + g * 4;
#pragma unroll
        for (int j = 0; j < 4; ++j) {
          if (kbase + j > qrow0) accs0[ct][j] = -1e30f;
          if (kbase + j > qrow1) accs1[ct][j] = -1e30f;
        }
      }
    }

    // lane-local max trees
    float a0 = fmaxf(fmaxf(accs0[0][0], accs0[0][1]), fmaxf(accs0[0][2], accs0[0][3]));
    float a1 = fmaxf(fmaxf(accs0[1][0], accs0[1][1]), fmaxf(accs0[1][2], accs0[1][3]));
    float a2 = fmaxf(fmaxf(accs0[2][0], accs0[2][1]), fmaxf(accs0[2][2], accs0[2][3]));
    float a3 = fmaxf(fmaxf(accs0[3][0], accs0[3][1]), fmaxf(accs0[3][2], accs0[3][3]));
    float pm0 = fmaxf(fmaxf(a0, a1), fmaxf(a2, a3));
    float b0 = fmaxf(fmaxf(accs1[0][0], accs1[0][1]), fmaxf(accs1[0][2], accs1[0][3]));
    float b1 = fmaxf(fmaxf(accs1[1][0], accs1[1][1]), fmaxf(accs1[1][2], accs1[1][3]));
    float b2 = fmaxf(fmaxf(accs1[2][0], accs1[2][1]), fmaxf(accs1[2][2], accs1[2][3]));
    float b3 = fmaxf(fmaxf(accs1[3][0], accs1[3][1]), fmaxf(accs1[3][2], accs1[3][3]));
    float pm1 = fmaxf(fmaxf(b0, b1), fmaxf(b2, b3));

    // defer-max: common path has NO cross-lane ops
    if (!__all((pm0 <= m0 + DEFER_THR) & (pm1 <= m1 + DEFER_THR))) {
      pm0 = fmaxf(pm0, __shfl_xor(pm0, 16));
      pm0 = fmaxf(pm0, __shfl_xor(pm0, 32));
      pm1 = fmaxf(pm1, __shfl_xor(pm1, 16));
      pm1 = fmaxf(pm1, __shfl_xor(pm1, 32));
      float mn0 = fmaxf(m0, pm0);
      float c0f = __builtin_amdgcn_exp2f(m0 - mn0);
      l0 *= c0f; m0 = mn0;
      float mn1 = fmaxf(m1, pm1);
      float c1f = __builtin_amdgcn_exp2f(m1 - mn1);
      l1 *= c1f; m1 = mn1;
#pragma unroll
      for (int dt = 0; dt < 4; ++dt)
#pragma unroll
        for (int j = 0; j < 4; ++j) {
          acc_o0[dt][j] *= c0f;
          acc_o1[dt][j] *= c1f;
        }
    }

    // P = exp2(S - m) packed into K=32 permuted-slot fragments
    float rs0 = 0.f, rs1 = 0.f;
    short8 pk80[2], pk81[2];
#pragma unroll
    for (int t2 = 0; t2 < 2; ++t2) {
      float p0 = __builtin_amdgcn_exp2f(accs0[2 * t2][0] - m0);
      float p1 = __builtin_amdgcn_exp2f(accs0[2 * t2][1] - m0);
      float p2 = __builtin_amdgcn_exp2f(accs0[2 * t2][2] - m0);
      float p3 = __builtin_amdgcn_exp2f(accs0[2 * t2][3] - m0);
      float p4 = __builtin_amdgcn_exp2f(accs0[2 * t2 + 1][0] - m0);
      float p5 = __builtin_amdgcn_exp2f(accs0[2 * t2 + 1][1] - m0);
      float p6 = __builtin_amdgcn_exp2f(accs0[2 * t2 + 1][2] - m0);
      float p7 = __builtin_amdgcn_exp2f(accs0[2 * t2 + 1][3] - m0);
      rs0 += ((p0 + p1) + (p2 + p3)) + ((p4 + p5) + (p6 + p7));
      union { unsigned u[4]; short8 v; } pu;
      pu.u[0] = cvtpk_bf16(p0, p1);
      pu.u[1] = cvtpk_bf16(p2, p3);
      pu.u[2] = cvtpk_bf16(p4, p5);
      pu.u[3] = cvtpk_bf16(p6, p7);
      pk80[t2] = pu.v;
      float q0e = __builtin_amdgcn_exp2f(accs1[2 * t2][0] - m1);
      float q1e = __builtin_amdgcn_exp2f(accs1[2 * t2][1] - m1);
      float q2e = __builtin_amdgcn_exp2f(accs1[2 * t2][2] - m1);
      float q3e = __builtin_amdgcn_exp2f(accs1[2 * t2][3] - m1);
      float q4e = __builtin_amdgcn_exp2f(accs1[2 * t2 + 1][0] - m1);
      float q5e = __builtin_amdgcn_exp2f(accs1[2 * t2 + 1][1] - m1);
      float q6e = __builtin_amdgcn_exp2f(accs1[2 * t2 + 1][2] - m1);
      float q7e = __builtin_amdgcn_exp2f(accs1[2 * t2 + 1][3] - m1);
      rs1 += ((q0e + q1e) + (q2e + q3e)) + ((q4e + q5e) + (q6e + q7e));
      union { unsigned u[4]; short8 v; } qu;
      qu.u[0] = cvtpk_bf16(q0e, q1e);
      qu.u[1] = cvtpk_bf16(q2e, q3e);
      qu.u[2] = cvtpk_bf16(q4e, q5e);
      qu.u[3] = cvtpk_bf16(q6e, q7e);
      pk81[t2] = qu.v;
    }
    l0 += rs0;
    l1 += rs1;

    // swapped PV dual, K=32 permuted slots (V fragments shared across qsets)
    __builtin_amdgcn_s_setprio(1);
#pragma unroll
    for (int dt = 0; dt < 4; ++dt) {
      int rb = (dt * 16 + l15) * 64;
#pragma unroll
      for (int t2 = 0; t2 < 2; ++t2) {
        union { short4v hh[2]; short8 v; } vu;
        vu.hh[0] = *(const short4v*)&Vc[rb + voff[2 * t2]];
        vu.hh[1] = *(const short4v*)&Vc[rb + voff[2 * t2 + 1]];
        acc_o0[dt] = __builtin_amdgcn_mfma_f32_16x16x32_bf16(vu.v, pk80[t2], acc_o0[dt], 0, 0, 0);
        acc_o1[dt] = __builtin_amdgcn_mfma_f32_16x16x32_bf16(vu.v, pk81[t2], acc_o1[dt], 0, 0, 0);
      }
    }
    __builtin_amdgcn_s_setprio(0);

    if (more) {
      *(short8*)&Ks[cur ^ 1][wo] = nk;
      *(short8*)&Vs[cur ^ 1][wo] = nv;
      if (it + 4 <= last) {
        int kv4 = kv0 + 256;
        nk = *(const short8*)&kh[(size_t)(kv4 + sr) * DHEAD + scc];
        nv = *(const short8*)&vh[(size_t)sr * S_LEN + kv4 + scc];
      }
    }
    __syncthreads();
    cur ^= 1;
  }

  // epilogue: reduce l, dead-row handling, store partial + (m,l)
  l0 += __shfl_xor(l0, 16);
  l0 += __shfl_xor(l0, 32);
  l1 += __shfl_xor(l1, 16);
  l1 += __shfl_xor(l1, 32);
  bool dead0 = (m0 == -1e30f);
  bool dead1 = (m1 == -1e30f);
  float rl0 = (!dead0 && l0 > 0.f) ? 1.f / l0 : 0.f;
  float rl1 = (!dead1 && l1 > 0.f) ? 1.f / l1 : 0.f;
#pragma unroll
  for (int dt = 0; dt < 4; ++dt) {
    ushort4 o0, o1;
    o0.x = f2bf(acc_o0[dt][0] * rl0);
    o0.y = f2bf(acc_o0[dt][1] * rl0);
    o0.z = f2bf(acc_o0[dt][2] * rl0);
    o0.w = f2bf(acc_o0[dt][3] * rl0);
    o1.x = f2bf(acc_o1[dt][0] * rl1);
    o1.y = f2bf(acc_o1[dt][1] * rl1);
    o1.z = f2bf(acc_o1[dt][2] * rl1);
    o1.w = f2bf(acc_o1[dt][3] * rl1);
    *(ushort4*)&Pc[(size_t)qrow0 * D_EMB + h * DHEAD + dt * 16 + g * 4] = o0;
    *(ushort4*)&Pc[(size_t)qrow1 * D_EMB + h * DHEAD + dt * 16 + g * 4] = o1;
  }
  if (g == 0)
    ml[(size_t)(c * NH + h) * S_LEN + qrow0] = make_float2(m0, dead0 ? 0.f : l0);
  if (g == 1)
    ml[(size_t)(c * NH + h) * S_LEN + qrow1] = make_float2(m1, dead1 ? 0.f : l1);
}

// ---------------- combine the two KV-chunk partials ----------------
__global__ __launch_bounds__(256) void combine_kernel(const ushort* __restrict__ P0,
                                                      const ushort* __restrict__ P1,
                                                      const float2* __restrict__ ml,
                                                      ushort* __restrict__ Out) {
  int idx = blockIdx.x * 256 + threadIdx.x;
  int row = idx >> 7;
  int cb = (idx & 127) * 8;
  int h = cb >> 6;
  float2 e0 = ml[(size_t)h * S_LEN + row];
  float2 e1 = ml[(size_t)(NH + h) * S_LEN + row];
  float mm = fmaxf(e0.x, e1.x);
  float w0 = e0.y * __builtin_amdgcn_exp2f(e0.x - mm);
  float w1 = e1.y * __builtin_amdgcn_exp2f(e1.x - mm);
  float inv = 1.f / (w0 + w1);
  w0 *= inv; w1 *= inv;
  size_t base = (size_t)row * D_EMB + cb;
  short8 a = *(const short8*)&P0[base];
  short8 b = *(const short8*)&P1[base];
  short8 o;
#pragma unroll
  for (int i = 0; i < 8; ++i) {
    float fv = w0 * bf2f((unsigned short)a[i]) + w1 * bf2f((unsigned short)b[i]);
    o[i] = (short)f2bf(fv);
  }
  *(short8*)&Out[base] = o;
}

extern "C" void kernel_launch(void* const* d_in, const int* in_sizes, int n_in,
                              void* d_out, int out_size, void* d_ws, size_t ws_size,
                              hipStream_t stream) {
  const float* x = (const float*)d_in[0];
  const float* W_in = (const float*)d_in[1];
  const float* b_in = (const float*)d_in[2];
  const float* W_out = (const float*)d_in[3];
  const float* b_out = (const float*)d_in[4];
  float* out = (float*)d_out;
  ushort* ws = (ushort*)d_ws;

  ushort* P0 = ws + OFF_ATTN;
  ushort* P1 = ws + OFF_XB;                // x_bf16 dead after gemm1
  float2* ml = (float2*)(ws + OFF_WINT);   // W_in^T dead after gemm1

  cvt_bf16_kernel<<<4096, 256, 0, stream>>>(x, ws + OFF_XB, S_LEN * D_EMB);
  transpose_cvt_kernel<<<dim3(N3 / 32, D_EMB / 32), 256, 0, stream>>>(W_in, ws + OFF_WINT, D_EMB, N3);
  transpose_cvt_kernel<<<dim3(D_EMB / 32, D_EMB / 32), 256, 0, stream>>>(W_out, ws + OFF_WOUTT, D_EMB, D_EMB);
  gemm1_8phase<<<dim3(12, 16), 512, 0, stream>>>(
      ws + OFF_XB, ws + OFF_WINT, b_in, ws + OFF_Q);
  attn_kernel<<<512, 512, 0, stream>>>(
      ws + OFF_Q, ws + OFF_Q + 4194304u, ws + OFF_Q + 8388608u, P0, P1, ml);
  combine_kernel<<<(S_LEN * D_EMB / 8) / 256, 256, 0, stream>>>(P0, P1, ml, P0);
  gemm2_kernel<<<dim3(D_EMB / 128, S_LEN / 128), 512, 0, stream>>>(
      P0, ws + OFF_WOUTT, b_out, out, D_EMB, D_EMB);
}

// Round 14
// 148.602 us; speedup vs baseline: 1.0868x; 1.0868x over previous
//
#include <hip/hip_runtime.h>
#include <stdint.h>

#define S_LEN 4096
#define D_EMB 1024
#define NH 16
#define DHEAD 64
#define N3 3072

typedef __attribute__((ext_vector_type(8))) short short8;
typedef __attribute__((ext_vector_type(4))) short short4v;
typedef __attribute__((ext_vector_type(4))) float f32x4;

// workspace layout (ushort elements)
#define OFF_XB    0u         // x bf16; reused as chunk-1 attn partial after gemm1
#define OFF_WINT  4194304u   // W_in^T bf16; reused as attn (m,l) after gemm1
#define OFF_WOUTT 7340032u   // W_out^T bf16 (live until gemm2)
#define OFF_Q     8388608u   // q [H][S][64], k [H][S][64], v^T [H][64][S]
#define OFF_ATTN  20971520u  // chunk-0 partial / combined attn out [4096][1024]

// 0.125 (1/sqrt(64)) * log2(e)
#define QSCALE 0.1803368801111204f
#define DEFER_THR 11.0f

__device__ __forceinline__ unsigned short f2bf(float f) {
  unsigned u = __float_as_uint(f);
  unsigned r = u + 0x7FFFu + ((u >> 16) & 1u);
  return (unsigned short)(r >> 16);
}
__device__ __forceinline__ float bf2f(unsigned short b) {
  return __uint_as_float(((unsigned)b) << 16);
}
__device__ __forceinline__ unsigned cvtpk_bf16(float lo, float hi) {
  unsigned r;
  asm("v_cvt_pk_bf16_f32 %0, %1, %2" : "=v"(r) : "v"(lo), "v"(hi));
  return r;
}
__device__ __forceinline__ void gload16(const void* g, void* l) {
  __builtin_amdgcn_global_load_lds((const __attribute__((address_space(1))) void*)g,
                                   (__attribute__((address_space(3))) void*)l, 16, 0, 0);
}

// ---------------- elementwise f32 -> bf16 ----------------
__global__ __launch_bounds__(256) void cvt_bf16_kernel(const float* __restrict__ src,
                                                       ushort* __restrict__ dst, int n) {
  int i = (blockIdx.x * 256 + threadIdx.x) * 4;
  if (i + 3 < n) {
    float4 v = *(const float4*)(src + i);
    ushort4 o;
    o.x = f2bf(v.x); o.y = f2bf(v.y); o.z = f2bf(v.z); o.w = f2bf(v.w);
    *(ushort4*)(dst + i) = o;
  }
}

// ---------------- transpose + cast: src[R][C] f32 -> dst[C][R] bf16 ----------------
__global__ __launch_bounds__(256) void transpose_cvt_kernel(const float* __restrict__ src,
                                                            ushort* __restrict__ dst,
                                                            int R, int C) {
  __shared__ float tile[32][33];
  int tx = threadIdx.x & 31, ty = threadIdx.x >> 5;
  int c0 = blockIdx.x * 32, r0 = blockIdx.y * 32;
#pragma unroll
  for (int i = 0; i < 32; i += 8)
    tile[ty + i][tx] = src[(size_t)(r0 + ty + i) * C + c0 + tx];
  __syncthreads();
#pragma unroll
  for (int i = 0; i < 32; i += 8)
    dst[(size_t)(c0 + ty + i) * R + r0 + tx] = f2bf(tile[tx][ty + i]);
}

// ---------------- GEMM1: 256x256 tile, 8-phase counted-vmcnt pipeline (r12) ----------------
__global__ __launch_bounds__(512, 2) void gemm1_8phase(const ushort* __restrict__ A,
                                                       const ushort* __restrict__ Bt,
                                                       const float* __restrict__ bias,
                                                       ushort* __restrict__ o16) {
  __shared__ ushort L[65536];   // A halves at 0..32767, B halves at 32768..
  const int K = 1024;
  int tid = threadIdx.x, w = tid >> 6, lane = tid & 63;
  int wr = w >> 2, wc = w & 3;
  int l15 = lane & 15, g = lane >> 4;
  int lr = lane >> 3, lc = lane & 7;
  int swcol = (lc ^ lr) * 8;       // pre-swizzled global column slot
  int rxor = (l15 & 7) << 3;       // read-side slot XOR (ushort units)
  int id = blockIdx.y * 12 + blockIdx.x;
  int id2 = (id & 7) * 24 + (id >> 3);
  int bm = (id2 / 12) * 256, bn = (id2 % 12) * 256;

  f32x4 acc[8][4];
#pragma unroll
  for (int m = 0; m < 8; ++m)
#pragma unroll
    for (int n = 0; n < 4; ++n) acc[m][n] = (f32x4){0.f, 0.f, 0.f, 0.f};

  auto stageA = [&](int t, int h) {
#pragma unroll
    for (int r2 = 0; r2 < 2; ++r2)
      gload16(A + (size_t)(bm + h * 128 + r2 * 64 + w * 8 + lr) * K + t * 64 + swcol,
              &L[((t & 1) * 2 + h) * 8192 + r2 * 4096 + w * 512]);
  };
  auto stageB = [&](int t, int h) {
#pragma unroll
    for (int r2 = 0; r2 < 2; ++r2)
      gload16(Bt + (size_t)(bn + h * 128 + r2 * 64 + w * 8 + lr) * K + t * 64 + swcol,
              &L[32768 + ((t & 1) * 2 + h) * 8192 + r2 * 4096 + w * 512]);
  };

  short8 bf[4][2], af[2][2];
  auto readB = [&](int tb) {
    int base = 32768 + (tb * 2 + (wc >> 1)) * 8192 + (wc & 1) * 4096;
#pragma unroll
    for (int n = 0; n < 4; ++n)
#pragma unroll
      for (int ks = 0; ks < 2; ++ks)
        bf[n][ks] = *(const short8*)&L[base + (n * 16 + l15) * 64 + ((ks * 32 + g * 8) ^ rxor)];
  };
  auto readA2 = [&](int tb, int m0) {
    int base = (tb * 2 + wr) * 8192;
#pragma unroll
    for (int mi = 0; mi < 2; ++mi)
#pragma unroll
      for (int ks = 0; ks < 2; ++ks)
        af[mi][ks] = *(const short8*)&L[base + ((m0 + mi) * 16 + l15) * 64 + ((ks * 32 + g * 8) ^ rxor)];
  };
  auto mfma8 = [&](int m0) {
#pragma unroll
    for (int mi = 0; mi < 2; ++mi)
#pragma unroll
      for (int n = 0; n < 4; ++n)
#pragma unroll
        for (int ks = 0; ks < 2; ++ks)
          acc[m0 + mi][n] =
              __builtin_amdgcn_mfma_f32_16x16x32_bf16(af[mi][ks], bf[n][ks], acc[m0 + mi][n], 0, 0, 0);
  };

#define BAR() __builtin_amdgcn_s_barrier()
#define LGK0() asm volatile("s_waitcnt lgkmcnt(0)" ::: "memory")
#define VM4() asm volatile("s_waitcnt vmcnt(4)" ::: "memory")
#define VM0() asm volatile("s_waitcnt vmcnt(0)" ::: "memory")

  stageA(0, 0); stageA(0, 1); stageB(0, 0); stageB(0, 1);
  stageB(1, 0); stageB(1, 1);
  VM4();
  BAR();

  for (int i = 0; i < 8; ++i) {
    int T = 2 * i;
    bool more = (T + 2 < 16);
    readB(0); readA2(0, 0); stageA(T + 1, 0);
    BAR(); LGK0();
    __builtin_amdgcn_s_setprio(1); mfma8(0); __builtin_amdgcn_s_setprio(0);
    BAR();
    readA2(0, 2); stageA(T + 1, 1);
    BAR(); LGK0();
    __builtin_amdgcn_s_setprio(1); mfma8(2); __builtin_amdgcn_s_setprio(0);
    BAR();
    readA2(0, 4); if (more) stageB(T + 2, 0);
    BAR(); LGK0();
    __builtin_amdgcn_s_setprio(1); mfma8(4); __builtin_amdgcn_s_setprio(0);
    BAR();
    readA2(0, 6); if (more) stageB(T + 2, 1);
    BAR(); LGK0();
    __builtin_amdgcn_s_setprio(1); mfma8(6); __builtin_amdgcn_s_setprio(0);
    if (more) VM4(); else VM0();
    BAR();
    readB(1); readA2(1, 0); if (more) stageA(T + 2, 0);
    BAR(); LGK0();
    __builtin_amdgcn_s_setprio(1); mfma8(0); __builtin_amdgcn_s_setprio(0);
    BAR();
    readA2(1, 2); if (more) stageA(T + 2, 1);
    BAR(); LGK0();
    __builtin_amdgcn_s_setprio(1); mfma8(2); __builtin_amdgcn_s_setprio(0);
    BAR();
    readA2(1, 4); if (more) stageB(T + 3, 0);
    BAR(); LGK0();
    __builtin_amdgcn_s_setprio(1); mfma8(4); __builtin_amdgcn_s_setprio(0);
    BAR();
    readA2(1, 6); if (more) stageB(T + 3, 1);
    BAR(); LGK0();
    __builtin_amdgcn_s_setprio(1); mfma8(6); __builtin_amdgcn_s_setprio(0);
    if (more) VM4(); else VM0();
    BAR();
  }
#undef BAR
#undef LGK0
#undef VM4
#undef VM0

#pragma unroll
  for (int m = 0; m < 8; ++m) {
    int rbase = bm + wr * 128 + m * 16 + g * 4;
#pragma unroll
    for (int n = 0; n < 4; ++n) {
      int c = bn + wc * 64 + n * 16 + l15;
      float bv = bias[c];
      int which = c >> 10, cc = c & 1023, hh = cc >> 6, dcol = cc & 63;
      if (which == 2) {
        ushort4 o;
        o.x = f2bf(acc[m][n][0] + bv);
        o.y = f2bf(acc[m][n][1] + bv);
        o.z = f2bf(acc[m][n][2] + bv);
        o.w = f2bf(acc[m][n][3] + bv);
        *(ushort4*)&o16[8388608u + (size_t)hh * (DHEAD * (size_t)S_LEN) +
                        (size_t)dcol * S_LEN + rbase] = o;
      } else {
        float qs = (which == 0) ? QSCALE : 1.0f;
        ushort* dst = o16 + (size_t)which * 4194304u +
                      (size_t)hh * (S_LEN * DHEAD) + dcol;
#pragma unroll
        for (int j = 0; j < 4; ++j)
          dst[(size_t)(rbase + j) * DHEAD] = f2bf((acc[m][n][j] + bv) * qs);
      }
    }
  }
}

// ---------------- GEMM2: 128x128 tile, 512 threads (8 waves, 2 waves/SIMD) ----------------
#define BK 64

__global__ __launch_bounds__(512) void gemm2_kernel(const ushort* __restrict__ A,
                                                    const ushort* __restrict__ Bt,
                                                    const float* __restrict__ bias,
                                                    float* __restrict__ o32,
                                                    int N, int K) {
  __shared__ ushort As[128 * 64];
  __shared__ ushort Bs[128 * 64];
  int tid = threadIdx.x, w = tid >> 6, lane = tid & 63;
  int wr = w >> 2, wc = w & 3;           // 2M x 4N waves, per-wave 64x32
  int l15 = lane & 15, g = lane >> 4;
  int lr = lane >> 3, lc = lane & 7;
  int gx = gridDim.x;
  int id = blockIdx.y * gx + blockIdx.x;
  int q8 = (gx * gridDim.y) >> 3;
  int id2 = (id & 7) * q8 + (id >> 3);
  int bm = (id2 / gx) * 128, bn = (id2 % gx) * 128;
  f32x4 acc[4][2];
#pragma unroll
  for (int m = 0; m < 4; ++m)
#pragma unroll
    for (int n = 0; n < 2; ++n) acc[m][n] = (f32x4){0.f, 0.f, 0.f, 0.f};

  for (int k0 = 0; k0 < K; k0 += BK) {
    __syncthreads();
#pragma unroll
    for (int i = 0; i < 2; ++i) {
      int row = i * 64 + w * 8 + lr;
      gload16(A + (size_t)(bm + row) * K + k0 + lc * 8, &As[i * 4096 + w * 512]);
      gload16(Bt + (size_t)(bn + row) * K + k0 + lc * 8, &Bs[i * 4096 + w * 512]);
    }
    __syncthreads();
    short8 a[4][2], b[2][2];
#pragma unroll
    for (int m = 0; m < 4; ++m)
#pragma unroll
      for (int t = 0; t < 2; ++t)
        a[m][t] = *(const short8*)&As[(wr * 64 + m * 16 + l15) * 64 + t * 32 + g * 8];
#pragma unroll
    for (int n = 0; n < 2; ++n)
#pragma unroll
      for (int t = 0; t < 2; ++t)
        b[n][t] = *(const short8*)&Bs[(wc * 32 + n * 16 + l15) * 64 + t * 32 + g * 8];
#pragma unroll
    for (int m = 0; m < 4; ++m)
#pragma unroll
      for (int n = 0; n < 2; ++n)
#pragma unroll
        for (int t = 0; t < 2; ++t)
          acc[m][n] = __builtin_amdgcn_mfma_f32_16x16x32_bf16(a[m][t], b[n][t], acc[m][n], 0, 0, 0);
  }

#pragma unroll
  for (int m = 0; m < 4; ++m) {
    int rbase = bm + wr * 64 + m * 16 + g * 4;
#pragma unroll
    for (int n = 0; n < 2; ++n) {
      int c = bn + wc * 32 + n * 16 + l15;
      float bv = bias[c];
#pragma unroll
      for (int j = 0; j < 4; ++j)
        o32[(size_t)(rbase + j) * N + c] = acc[m][n][j] + bv;
    }
  }
}

// ---------------- causal flash attention: r12 body + split-KV x2 ----------------
// Q (pre-scaled, log2 units), K: [H][S][64].  Vt: [H][64][S].
// QBLK=128 (8 waves x 16 q-rows), KVBLK=64, XOR-swizzled dbuf LDS, ONE
// barrier/tile, PV via K=32 permuted slots.  Chunk c handles tiles it%2==c
// (disjoint KV reads). Grid 1024 x 512thr -> 4 blocks/CU, 32 waves/CU.
// Per-CU work uniform: (32-u)+(u+1)+(32-u)+(u+1) = 66 tile-units.
// Fully-masked rows (qt=0,c=1 rows<64) detected via m==-1e30 -> zeroed.
__global__ __launch_bounds__(512) void attn_kernel(const ushort* __restrict__ Q,
                                                   const ushort* __restrict__ Kg,
                                                   const ushort* __restrict__ Vtg,
                                                   ushort* __restrict__ P0,
                                                   ushort* __restrict__ P1,
                                                   float2* __restrict__ ml) {
  __shared__ ushort Ks[2][64 * 64];
  __shared__ ushort Vs[2][64 * 64];
  int bid = blockIdx.x;
  int c = bid >> 9;
  int r = bid & 511;
  int h = r & 15;
  int qt = (r < 256) ? (31 - (r >> 4)) : ((r - 256) >> 4);
  int q0 = qt * 128;
  int tid = threadIdx.x, w = tid >> 6, lane = tid & 63;
  int l15 = lane & 15, g = lane >> 4;
  const ushort* qh = Q + (size_t)h * (S_LEN * DHEAD);
  const ushort* kh = Kg + (size_t)h * (S_LEN * DHEAD);
  const ushort* vh = Vtg + (size_t)h * (DHEAD * (size_t)S_LEN);
  ushort* Pc = c ? P1 : P0;
  int sr = tid >> 3;
  int scc = (tid & 7) * 8;
  int wo = sr * 64 + (((scc * 2) ^ ((sr & 7) << 4)) >> 1);
  int kxor = (l15 & 7) << 4;
  int koff0 = ((g * 16) ^ kxor) >> 1;
  int koff1 = ((64 + g * 16) ^ kxor) >> 1;
  int voff[4];
#pragma unroll
  for (int ct = 0; ct < 4; ++ct) voff[ct] = ((ct * 32 + g * 8) ^ kxor) >> 1;

  int qrow = q0 + w * 16 + l15;
  short8 aq[2];
#pragma unroll
  for (int t = 0; t < 2; ++t)
    aq[t] = *(const short8*)&qh[(size_t)qrow * DHEAD + t * 32 + g * 8];

  f32x4 acc_o[4];
#pragma unroll
  for (int dt = 0; dt < 4; ++dt) acc_o[dt] = (f32x4){0.f, 0.f, 0.f, 0.f};
  float m = -1e30f, l = 0.f;
  int last = 2 * qt + 1;       // chunk c: it = c, c+2, ..., <= last (>=1 tile)

  // prologue: stage tile c (swizzled); prefetch tile c+2 if present
  {
    int kv0 = c * 64;
    short8 ka = *(const short8*)&kh[(size_t)(kv0 + sr) * DHEAD + scc];
    short8 va = *(const short8*)&vh[(size_t)sr * S_LEN + kv0 + scc];
    *(short8*)&Ks[0][wo] = ka;
    *(short8*)&Vs[0][wo] = va;
  }
  short8 nk, nv;
  if (c + 2 <= last) {
    int kv2 = (c + 2) * 64;
    nk = *(const short8*)&kh[(size_t)(kv2 + sr) * DHEAD + scc];
    nv = *(const short8*)&vh[(size_t)sr * S_LEN + kv2 + scc];
  }
  __syncthreads();
  int cur = 0;

  for (int it = c; it <= last; it += 2) {
    int kv0 = it * 64;
    bool more = (it + 2 <= last);
    const ushort* Kc = Ks[cur];
    const ushort* Vc = Vs[cur];

    f32x4 accs[4];
#pragma unroll
    for (int ct = 0; ct < 4; ++ct) accs[ct] = (f32x4){0.f, 0.f, 0.f, 0.f};
    __builtin_amdgcn_s_setprio(1);
#pragma unroll
    for (int ct = 0; ct < 4; ++ct) {
      int rb = (ct * 16 + l15) * 64;
      short8 kf0 = *(const short8*)&Kc[rb + koff0];
      short8 kf1 = *(const short8*)&Kc[rb + koff1];
      accs[ct] = __builtin_amdgcn_mfma_f32_16x16x32_bf16(kf0, aq[0], accs[ct], 0, 0, 0);
      accs[ct] = __builtin_amdgcn_mfma_f32_16x16x32_bf16(kf1, aq[1], accs[ct], 0, 0, 0);
    }
    __builtin_amdgcn_s_setprio(0);

    if (it >= 2 * qt) {  // diagonal band: causal mask
#pragma unroll
      for (int ct = 0; ct < 4; ++ct) {
        int kbase = kv0 + ct * 16 + g * 4;
#pragma unroll
        for (int j = 0; j < 4; ++j)
          if (kbase + j > qrow) accs[ct][j] = -1e30f;
      }
    }

    float a0 = fmaxf(fmaxf(accs[0][0], accs[0][1]), fmaxf(accs[0][2], accs[0][3]));
    float a1 = fmaxf(fmaxf(accs[1][0], accs[1][1]), fmaxf(accs[1][2], accs[1][3]));
    float a2 = fmaxf(fmaxf(accs[2][0], accs[2][1]), fmaxf(accs[2][2], accs[2][3]));
    float a3 = fmaxf(fmaxf(accs[3][0], accs[3][1]), fmaxf(accs[3][2], accs[3][3]));
    float pm = fmaxf(fmaxf(a0, a1), fmaxf(a2, a3));

    if (!__all(pm <= m + DEFER_THR)) {
      pm = fmaxf(pm, __shfl_xor(pm, 16));
      pm = fmaxf(pm, __shfl_xor(pm, 32));
      float mnew = fmaxf(m, pm);
      float corr = __builtin_amdgcn_exp2f(m - mnew);
      l *= corr; m = mnew;
#pragma unroll
      for (int dt = 0; dt < 4; ++dt)
#pragma unroll
        for (int j = 0; j < 4; ++j) acc_o[dt][j] *= corr;
    }

    float rs = 0.f;
    short8 pk8[2];
#pragma unroll
    for (int t2 = 0; t2 < 2; ++t2) {
      float p0 = __builtin_amdgcn_exp2f(accs[2 * t2][0] - m);
      float p1 = __builtin_amdgcn_exp2f(accs[2 * t2][1] - m);
      float p2 = __builtin_amdgcn_exp2f(accs[2 * t2][2] - m);
      float p3 = __builtin_amdgcn_exp2f(accs[2 * t2][3] - m);
      float p4 = __builtin_amdgcn_exp2f(accs[2 * t2 + 1][0] - m);
      float p5 = __builtin_amdgcn_exp2f(accs[2 * t2 + 1][1] - m);
      float p6 = __builtin_amdgcn_exp2f(accs[2 * t2 + 1][2] - m);
      float p7 = __builtin_amdgcn_exp2f(accs[2 * t2 + 1][3] - m);
      rs += ((p0 + p1) + (p2 + p3)) + ((p4 + p5) + (p6 + p7));
      union { unsigned u[4]; short8 v; } pu;
      pu.u[0] = cvtpk_bf16(p0, p1);
      pu.u[1] = cvtpk_bf16(p2, p3);
      pu.u[2] = cvtpk_bf16(p4, p5);
      pu.u[3] = cvtpk_bf16(p6, p7);
      pk8[t2] = pu.v;
    }
    l += rs;

    __builtin_amdgcn_s_setprio(1);
#pragma unroll
    for (int dt = 0; dt < 4; ++dt) {
      int rb = (dt * 16 + l15) * 64;
#pragma unroll
      for (int t2 = 0; t2 < 2; ++t2) {
        union { short4v hh[2]; short8 v; } vu;
        vu.hh[0] = *(const short4v*)&Vc[rb + voff[2 * t2]];
        vu.hh[1] = *(const short4v*)&Vc[rb + voff[2 * t2 + 1]];
        acc_o[dt] = __builtin_amdgcn_mfma_f32_16x16x32_bf16(vu.v, pk8[t2], acc_o[dt], 0, 0, 0);
      }
    }
    __builtin_amdgcn_s_setprio(0);

    if (more) {
      *(short8*)&Ks[cur ^ 1][wo] = nk;
      *(short8*)&Vs[cur ^ 1][wo] = nv;
      if (it + 4 <= last) {
        int kv4 = kv0 + 256;
        nk = *(const short8*)&kh[(size_t)(kv4 + sr) * DHEAD + scc];
        nv = *(const short8*)&vh[(size_t)sr * S_LEN + kv4 + scc];
      }
    }
    __syncthreads();
    cur ^= 1;
  }

  // epilogue: reduce l, dead-row handling, store partial + (m,l)
  l += __shfl_xor(l, 16);
  l += __shfl_xor(l, 32);
  bool dead = (m == -1e30f);   // row saw no valid key (qt=0,c=1 rows<64)
  float rl = (!dead && l > 0.f) ? 1.f / l : 0.f;
#pragma unroll
  for (int dt = 0; dt < 4; ++dt) {
    ushort4 o;
    o.x = f2bf(acc_o[dt][0] * rl);
    o.y = f2bf(acc_o[dt][1] * rl);
    o.z = f2bf(acc_o[dt][2] * rl);
    o.w = f2bf(acc_o[dt][3] * rl);
    *(ushort4*)&Pc[(size_t)qrow * D_EMB + h * DHEAD + dt * 16 + g * 4] = o;
  }
  if (g == 0)
    ml[(size_t)(c * NH + h) * S_LEN + qrow] = make_float2(m, dead ? 0.f : l);
}

// ---------------- combine the two KV-chunk partials ----------------
__global__ __launch_bounds__(256) void combine_kernel(const ushort* __restrict__ P0,
                                                      const ushort* __restrict__ P1,
                                                      const float2* __restrict__ ml,
                                                      ushort* __restrict__ Out) {
  int idx = blockIdx.x * 256 + threadIdx.x;
  int row = idx >> 7;
  int cb = (idx & 127) * 8;
  int h = cb >> 6;
  float2 e0 = ml[(size_t)h * S_LEN + row];
  float2 e1 = ml[(size_t)(NH + h) * S_LEN + row];
  float mm = fmaxf(e0.x, e1.x);
  float w0 = e0.y * __builtin_amdgcn_exp2f(e0.x - mm);
  float w1 = e1.y * __builtin_amdgcn_exp2f(e1.x - mm);
  float inv = 1.f / (w0 + w1);
  w0 *= inv; w1 *= inv;
  size_t base = (size_t)row * D_EMB + cb;
  short8 a = *(const short8*)&P0[base];
  short8 b = *(const short8*)&P1[base];
  short8 o;
#pragma unroll
  for (int i = 0; i < 8; ++i) {
    float fv = w0 * bf2f((unsigned short)a[i]) + w1 * bf2f((unsigned short)b[i]);
    o[i] = (short)f2bf(fv);
  }
  *(short8*)&Out[base] = o;
}

extern "C" void kernel_launch(void* const* d_in, const int* in_sizes, int n_in,
                              void* d_out, int out_size, void* d_ws, size_t ws_size,
                              hipStream_t stream) {
  const float* x = (const float*)d_in[0];
  const float* W_in = (const float*)d_in[1];
  const float* b_in = (const float*)d_in[2];
  const float* W_out = (const float*)d_in[3];
  const float* b_out = (const float*)d_in[4];
  float* out = (float*)d_out;
  ushort* ws = (ushort*)d_ws;

  ushort* P0 = ws + OFF_ATTN;
  ushort* P1 = ws + OFF_XB;                // x_bf16 dead after gemm1
  float2* ml = (float2*)(ws + OFF_WINT);   // W_in^T dead after gemm1

  cvt_bf16_kernel<<<4096, 256, 0, stream>>>(x, ws + OFF_XB, S_LEN * D_EMB);
  transpose_cvt_kernel<<<dim3(N3 / 32, D_EMB / 32), 256, 0, stream>>>(W_in, ws + OFF_WINT, D_EMB, N3);
  transpose_cvt_kernel<<<dim3(D_EMB / 32, D_EMB / 32), 256, 0, stream>>>(W_out, ws + OFF_WOUTT, D_EMB, D_EMB);
  gemm1_8phase<<<dim3(12, 16), 512, 0, stream>>>(
      ws + OFF_XB, ws + OFF_WINT, b_in, ws + OFF_Q);
  attn_kernel<<<1024, 512, 0, stream>>>(
      ws + OFF_Q, ws + OFF_Q + 4194304u, ws + OFF_Q + 8388608u, P0, P1, ml);
  combine_kernel<<<(S_LEN * D_EMB / 8) / 256, 256, 0, stream>>>(P0, P1, ml, P0);
  gemm2_kernel<<<dim3(D_EMB / 128, S_LEN / 128), 512, 0, stream>>>(
      P0, ws + OFF_WOUTT, b_out, out, D_EMB, D_EMB);
}

// Round 15
// 133.760 us; speedup vs baseline: 1.2074x; 1.1110x over previous
//
#include <hip/hip_runtime.h>
#include <stdint.h>

#define S_LEN 4096
#define D_EMB 1024
#define NH 16
#define DHEAD 64
#define N3 3072

typedef __attribute__((ext_vector_type(8))) short short8;
typedef __attribute__((ext_vector_type(4))) short short4v;
typedef __attribute__((ext_vector_type(4))) float f32x4;

// workspace layout (ushort elements)
#define OFF_XB    0u         // x bf16 [4096][1024]
#define OFF_WINT  4194304u   // W_in^T bf16
#define OFF_WOUTT 7340032u   // W_out^T bf16 (live until gemm2)
#define OFF_Q     8388608u   // q [H][S][64], k [H][S][64], v^T [H][64][S]
#define OFF_ATTN  20971520u  // attn out [4096][1024] bf16

// 0.125 (1/sqrt(64)) * log2(e)
#define QSCALE 0.1803368801111204f
#define DEFER_THR 11.0f

__device__ __forceinline__ unsigned short f2bf(float f) {
  unsigned u = __float_as_uint(f);
  unsigned r = u + 0x7FFFu + ((u >> 16) & 1u);
  return (unsigned short)(r >> 16);
}
__device__ __forceinline__ unsigned cvtpk_bf16(float lo, float hi) {
  unsigned r;
  asm("v_cvt_pk_bf16_f32 %0, %1, %2" : "=v"(r) : "v"(lo), "v"(hi));
  return r;
}
__device__ __forceinline__ void gload16(const void* g, void* l) {
  __builtin_amdgcn_global_load_lds((const __attribute__((address_space(1))) void*)g,
                                   (__attribute__((address_space(3))) void*)l, 16, 0, 0);
}

// ---------------- fused prep: cvt x + transpose W_in + transpose W_out ----------------
// blocks [0,4096): cvt x f32->bf16 (4 elems/thread)
// blocks [4096,7168): transpose W_in [1024][3072] -> [3072][1024] bf16
// blocks [7168,8192): transpose W_out [1024][1024] -> [1024][1024] bf16
__global__ __launch_bounds__(256) void prep_kernel(const float* __restrict__ x,
                                                   const float* __restrict__ W_in,
                                                   const float* __restrict__ W_out,
                                                   ushort* __restrict__ xb,
                                                   ushort* __restrict__ wint,
                                                   ushort* __restrict__ woutt) {
  __shared__ float tile[32][33];
  int b = blockIdx.x;
  if (b < 4096) {
    int i = (b * 256 + threadIdx.x) * 4;
    float4 v = *(const float4*)(x + i);
    ushort4 o;
    o.x = f2bf(v.x); o.y = f2bf(v.y); o.z = f2bf(v.z); o.w = f2bf(v.w);
    *(ushort4*)(xb + i) = o;
    return;
  }
  const float* src;
  ushort* dst;
  int R, C, bx, by;
  if (b < 7168) {
    int t = b - 4096;
    src = W_in; dst = wint; R = D_EMB; C = N3;
    bx = t % 96; by = t / 96;
  } else {
    int t = b - 7168;
    src = W_out; dst = woutt; R = D_EMB; C = D_EMB;
    bx = t & 31; by = t >> 5;
  }
  int tx = threadIdx.x & 31, ty = threadIdx.x >> 5;
  int c0 = bx * 32, r0 = by * 32;
#pragma unroll
  for (int i = 0; i < 32; i += 8)
    tile[ty + i][tx] = src[(size_t)(r0 + ty + i) * C + c0 + tx];
  __syncthreads();
#pragma unroll
  for (int i = 0; i < 32; i += 8)
    dst[(size_t)(c0 + ty + i) * R + r0 + tx] = f2bf(tile[tx][ty + i]);
}

// ---------------- GEMM1: 256x256 tile, 8-phase counted-vmcnt pipeline (r12) ----------------
__global__ __launch_bounds__(512, 2) void gemm1_8phase(const ushort* __restrict__ A,
                                                       const ushort* __restrict__ Bt,
                                                       const float* __restrict__ bias,
                                                       ushort* __restrict__ o16) {
  __shared__ ushort L[65536];   // A halves at 0..32767, B halves at 32768..
  const int K = 1024;
  int tid = threadIdx.x, w = tid >> 6, lane = tid & 63;
  int wr = w >> 2, wc = w & 3;
  int l15 = lane & 15, g = lane >> 4;
  int lr = lane >> 3, lc = lane & 7;
  int swcol = (lc ^ lr) * 8;       // pre-swizzled global column slot
  int rxor = (l15 & 7) << 3;       // read-side slot XOR (ushort units)
  int id = blockIdx.y * 12 + blockIdx.x;
  int id2 = (id & 7) * 24 + (id >> 3);
  int bm = (id2 / 12) * 256, bn = (id2 % 12) * 256;

  f32x4 acc[8][4];
#pragma unroll
  for (int m = 0; m < 8; ++m)
#pragma unroll
    for (int n = 0; n < 4; ++n) acc[m][n] = (f32x4){0.f, 0.f, 0.f, 0.f};

  auto stageA = [&](int t, int h) {
#pragma unroll
    for (int r2 = 0; r2 < 2; ++r2)
      gload16(A + (size_t)(bm + h * 128 + r2 * 64 + w * 8 + lr) * K + t * 64 + swcol,
              &L[((t & 1) * 2 + h) * 8192 + r2 * 4096 + w * 512]);
  };
  auto stageB = [&](int t, int h) {
#pragma unroll
    for (int r2 = 0; r2 < 2; ++r2)
      gload16(Bt + (size_t)(bn + h * 128 + r2 * 64 + w * 8 + lr) * K + t * 64 + swcol,
              &L[32768 + ((t & 1) * 2 + h) * 8192 + r2 * 4096 + w * 512]);
  };

  short8 bf[4][2], af[2][2];
  auto readB = [&](int tb) {
    int base = 32768 + (tb * 2 + (wc >> 1)) * 8192 + (wc & 1) * 4096;
#pragma unroll
    for (int n = 0; n < 4; ++n)
#pragma unroll
      for (int ks = 0; ks < 2; ++ks)
        bf[n][ks] = *(const short8*)&L[base + (n * 16 + l15) * 64 + ((ks * 32 + g * 8) ^ rxor)];
  };
  auto readA2 = [&](int tb, int m0) {
    int base = (tb * 2 + wr) * 8192;
#pragma unroll
    for (int mi = 0; mi < 2; ++mi)
#pragma unroll
      for (int ks = 0; ks < 2; ++ks)
        af[mi][ks] = *(const short8*)&L[base + ((m0 + mi) * 16 + l15) * 64 + ((ks * 32 + g * 8) ^ rxor)];
  };
  auto mfma8 = [&](int m0) {
#pragma unroll
    for (int mi = 0; mi < 2; ++mi)
#pragma unroll
      for (int n = 0; n < 4; ++n)
#pragma unroll
        for (int ks = 0; ks < 2; ++ks)
          acc[m0 + mi][n] =
              __builtin_amdgcn_mfma_f32_16x16x32_bf16(af[mi][ks], bf[n][ks], acc[m0 + mi][n], 0, 0, 0);
  };

#define BAR() __builtin_amdgcn_s_barrier()
#define LGK0() asm volatile("s_waitcnt lgkmcnt(0)" ::: "memory")
#define VM4() asm volatile("s_waitcnt vmcnt(4)" ::: "memory")
#define VM0() asm volatile("s_waitcnt vmcnt(0)" ::: "memory")

  stageA(0, 0); stageA(0, 1); stageB(0, 0); stageB(0, 1);
  stageB(1, 0); stageB(1, 1);
  VM4();
  BAR();

  for (int i = 0; i < 8; ++i) {
    int T = 2 * i;
    bool more = (T + 2 < 16);
    readB(0); readA2(0, 0); stageA(T + 1, 0);
    BAR(); LGK0();
    __builtin_amdgcn_s_setprio(1); mfma8(0); __builtin_amdgcn_s_setprio(0);
    BAR();
    readA2(0, 2); stageA(T + 1, 1);
    BAR(); LGK0();
    __builtin_amdgcn_s_setprio(1); mfma8(2); __builtin_amdgcn_s_setprio(0);
    BAR();
    readA2(0, 4); if (more) stageB(T + 2, 0);
    BAR(); LGK0();
    __builtin_amdgcn_s_setprio(1); mfma8(4); __builtin_amdgcn_s_setprio(0);
    BAR();
    readA2(0, 6); if (more) stageB(T + 2, 1);
    BAR(); LGK0();
    __builtin_amdgcn_s_setprio(1); mfma8(6); __builtin_amdgcn_s_setprio(0);
    if (more) VM4(); else VM0();
    BAR();
    readB(1); readA2(1, 0); if (more) stageA(T + 2, 0);
    BAR(); LGK0();
    __builtin_amdgcn_s_setprio(1); mfma8(0); __builtin_amdgcn_s_setprio(0);
    BAR();
    readA2(1, 2); if (more) stageA(T + 2, 1);
    BAR(); LGK0();
    __builtin_amdgcn_s_setprio(1); mfma8(2); __builtin_amdgcn_s_setprio(0);
    BAR();
    readA2(1, 4); if (more) stageB(T + 3, 0);
    BAR(); LGK0();
    __builtin_amdgcn_s_setprio(1); mfma8(4); __builtin_amdgcn_s_setprio(0);
    BAR();
    readA2(1, 6); if (more) stageB(T + 3, 1);
    BAR(); LGK0();
    __builtin_amdgcn_s_setprio(1); mfma8(6); __builtin_amdgcn_s_setprio(0);
    if (more) VM4(); else VM0();
    BAR();
  }
#undef BAR
#undef LGK0
#undef VM4
#undef VM0

#pragma unroll
  for (int m = 0; m < 8; ++m) {
    int rbase = bm + wr * 128 + m * 16 + g * 4;
#pragma unroll
    for (int n = 0; n < 4; ++n) {
      int c = bn + wc * 64 + n * 16 + l15;
      float bv = bias[c];
      int which = c >> 10, cc = c & 1023, hh = cc >> 6, dcol = cc & 63;
      if (which == 2) {
        ushort4 o;
        o.x = f2bf(acc[m][n][0] + bv);
        o.y = f2bf(acc[m][n][1] + bv);
        o.z = f2bf(acc[m][n][2] + bv);
        o.w = f2bf(acc[m][n][3] + bv);
        *(ushort4*)&o16[8388608u + (size_t)hh * (DHEAD * (size_t)S_LEN) +
                        (size_t)dcol * S_LEN + rbase] = o;
      } else {
        float qs = (which == 0) ? QSCALE : 1.0f;
        ushort* dst = o16 + (size_t)which * 4194304u +
                      (size_t)hh * (S_LEN * DHEAD) + dcol;
#pragma unroll
        for (int j = 0; j < 4; ++j)
          dst[(size_t)(rbase + j) * DHEAD] = f2bf((acc[m][n][j] + bv) * qs);
      }
    }
  }
}

// ---------------- GEMM2: 128x64 tile, 512 blocks (2 independent blocks/CU) ----------------
#define BK 64

__global__ __launch_bounds__(256) void gemm2_kernel(const ushort* __restrict__ A,
                                                    const ushort* __restrict__ Bt,
                                                    const float* __restrict__ bias,
                                                    float* __restrict__ o32,
                                                    int N, int K) {
  __shared__ ushort As[128 * 64];
  __shared__ ushort Bs[64 * 64];
  int tid = threadIdx.x, w = tid >> 6, lane = tid & 63;
  int wr = w >> 1, wc = w & 1;       // 2M x 2N waves; per-wave 64x32
  int l15 = lane & 15, g = lane >> 4;
  // XCD-bijective swizzle over 512 blocks
  int gx = gridDim.x;                 // 16 (N/64)
  int id = blockIdx.y * gx + blockIdx.x;
  int q8 = (gx * gridDim.y) >> 3;     // 64
  int id2 = (id & 7) * q8 + (id >> 3);
  int bm = (id2 / gx) * 128, bn = (id2 % gx) * 64;
  f32x4 acc[4][2];
#pragma unroll
  for (int m = 0; m < 4; ++m)
#pragma unroll
    for (int n = 0; n < 2; ++n) acc[m][n] = (f32x4){0.f, 0.f, 0.f, 0.f};

  int srow = lane >> 3;
  int scol = (lane & 7) * 8;

  for (int k0 = 0; k0 < K; k0 += BK) {
    __syncthreads();
#pragma unroll
    for (int i = 0; i < 4; ++i) {
      int ch = w * 4 + i;                  // 16 chunks of 8 rows (A)
      gload16(A + (size_t)(bm + ch * 8 + srow) * K + k0 + scol, &As[ch * 512]);
    }
#pragma unroll
    for (int i = 0; i < 2; ++i) {
      int ch = w * 2 + i;                  // 8 chunks of 8 rows (B)
      gload16(Bt + (size_t)(bn + ch * 8 + srow) * K + k0 + scol, &Bs[ch * 512]);
    }
    __syncthreads();
    short8 a[4][2], b[2][2];
#pragma unroll
    for (int m = 0; m < 4; ++m)
#pragma unroll
      for (int t = 0; t < 2; ++t)
        a[m][t] = *(const short8*)&As[(wr * 64 + m * 16 + l15) * 64 + t * 32 + g * 8];
#pragma unroll
    for (int n = 0; n < 2; ++n)
#pragma unroll
      for (int t = 0; t < 2; ++t)
        b[n][t] = *(const short8*)&Bs[(wc * 32 + n * 16 + l15) * 64 + t * 32 + g * 8];
#pragma unroll
    for (int m = 0; m < 4; ++m)
#pragma unroll
      for (int n = 0; n < 2; ++n)
#pragma unroll
        for (int t = 0; t < 2; ++t)
          acc[m][n] = __builtin_amdgcn_mfma_f32_16x16x32_bf16(a[m][t], b[n][t], acc[m][n], 0, 0, 0);
  }

#pragma unroll
  for (int m = 0; m < 4; ++m) {
    int rbase = bm + wr * 64 + m * 16 + g * 4;
#pragma unroll
    for (int n = 0; n < 2; ++n) {
      int c = bn + wc * 32 + n * 16 + l15;
      float bv = bias[c];
#pragma unroll
      for (int j = 0; j < 4; ++j)
        o32[(size_t)(rbase + j) * N + c] = acc[m][n][j] + bv;
    }
  }
}

// ---------------- causal flash attention (r12 exact, best measured 75.8us) ----------------
__global__ __launch_bounds__(512) void attn_kernel(const ushort* __restrict__ Q,
                                                   const ushort* __restrict__ Kg,
                                                   const ushort* __restrict__ Vtg,
                                                   ushort* __restrict__ O) {
  __shared__ ushort Ks[2][64 * 64];
  __shared__ ushort Vs[2][64 * 64];
  int bid = blockIdx.x;
  int h = bid & 15;
  int qt = (bid < 256) ? (31 - (bid >> 4)) : ((bid - 256) >> 4);
  int q0 = qt * 128;
  int tid = threadIdx.x, w = tid >> 6, lane = tid & 63;
  int l15 = lane & 15, g = lane >> 4;
  const ushort* qh = Q + (size_t)h * (S_LEN * DHEAD);
  const ushort* kh = Kg + (size_t)h * (S_LEN * DHEAD);
  const ushort* vh = Vtg + (size_t)h * (DHEAD * (size_t)S_LEN);
  int sr = tid >> 3;
  int scc = (tid & 7) * 8;
  int wo = sr * 64 + (((scc * 2) ^ ((sr & 7) << 4)) >> 1);
  int kxor = (l15 & 7) << 4;
  int koff0 = ((g * 16) ^ kxor) >> 1;
  int koff1 = ((64 + g * 16) ^ kxor) >> 1;
  int voff[4];
#pragma unroll
  for (int ct = 0; ct < 4; ++ct) voff[ct] = ((ct * 32 + g * 8) ^ kxor) >> 1;

  int qrow = q0 + w * 16 + l15;
  short8 aq[2];
#pragma unroll
  for (int t = 0; t < 2; ++t)
    aq[t] = *(const short8*)&qh[(size_t)qrow * DHEAD + t * 32 + g * 8];

  f32x4 acc_o[4];
#pragma unroll
  for (int dt = 0; dt < 4; ++dt) acc_o[dt] = (f32x4){0.f, 0.f, 0.f, 0.f};
  float m = -1e30f, l = 0.f;
  int last = 2 * qt + 1;

  {
    short8 ka = *(const short8*)&kh[(size_t)sr * DHEAD + scc];
    short8 va = *(const short8*)&vh[(size_t)sr * S_LEN + scc];
    *(short8*)&Ks[0][wo] = ka;
    *(short8*)&Vs[0][wo] = va;
  }
  short8 nk, nv;
  {
    nk = *(const short8*)&kh[(size_t)(64 + sr) * DHEAD + scc];
    nv = *(const short8*)&vh[(size_t)sr * S_LEN + 64 + scc];
  }
  __syncthreads();
  int cur = 0;

  for (int it = 0; it <= last; ++it) {
    int kv0 = it * 64;
    bool more = (it < last);
    const ushort* Kc = Ks[cur];
    const ushort* Vc = Vs[cur];

    f32x4 accs[4];
#pragma unroll
    for (int ct = 0; ct < 4; ++ct) accs[ct] = (f32x4){0.f, 0.f, 0.f, 0.f};
    __builtin_amdgcn_s_setprio(1);
#pragma unroll
    for (int ct = 0; ct < 4; ++ct) {
      int rb = (ct * 16 + l15) * 64;
      short8 kf0 = *(const short8*)&Kc[rb + koff0];
      short8 kf1 = *(const short8*)&Kc[rb + koff1];
      accs[ct] = __builtin_amdgcn_mfma_f32_16x16x32_bf16(kf0, aq[0], accs[ct], 0, 0, 0);
      accs[ct] = __builtin_amdgcn_mfma_f32_16x16x32_bf16(kf1, aq[1], accs[ct], 0, 0, 0);
    }
    __builtin_amdgcn_s_setprio(0);

    if (it >= 2 * qt) {
#pragma unroll
      for (int ct = 0; ct < 4; ++ct) {
        int kbase = kv0 + ct * 16 + g * 4;
#pragma unroll
        for (int j = 0; j < 4; ++j)
          if (kbase + j > qrow) accs[ct][j] = -1e30f;
      }
    }

    float a0 = fmaxf(fmaxf(accs[0][0], accs[0][1]), fmaxf(accs[0][2], accs[0][3]));
    float a1 = fmaxf(fmaxf(accs[1][0], accs[1][1]), fmaxf(accs[1][2], accs[1][3]));
    float a2 = fmaxf(fmaxf(accs[2][0], accs[2][1]), fmaxf(accs[2][2], accs[2][3]));
    float a3 = fmaxf(fmaxf(accs[3][0], accs[3][1]), fmaxf(accs[3][2], accs[3][3]));
    float pm = fmaxf(fmaxf(a0, a1), fmaxf(a2, a3));

    if (!__all(pm <= m + DEFER_THR)) {
      pm = fmaxf(pm, __shfl_xor(pm, 16));
      pm = fmaxf(pm, __shfl_xor(pm, 32));
      float mnew = fmaxf(m, pm);
      float corr = __builtin_amdgcn_exp2f(m - mnew);
      l *= corr; m = mnew;
#pragma unroll
      for (int dt = 0; dt < 4; ++dt)
#pragma unroll
        for (int j = 0; j < 4; ++j) acc_o[dt][j] *= corr;
    }

    float rs = 0.f;
    short8 pk8[2];
#pragma unroll
    for (int t2 = 0; t2 < 2; ++t2) {
      float p0 = __builtin_amdgcn_exp2f(accs[2 * t2][0] - m);
      float p1 = __builtin_amdgcn_exp2f(accs[2 * t2][1] - m);
      float p2 = __builtin_amdgcn_exp2f(accs[2 * t2][2] - m);
      float p3 = __builtin_amdgcn_exp2f(accs[2 * t2][3] - m);
      float p4 = __builtin_amdgcn_exp2f(accs[2 * t2 + 1][0] - m);
      float p5 = __builtin_amdgcn_exp2f(accs[2 * t2 + 1][1] - m);
      float p6 = __builtin_amdgcn_exp2f(accs[2 * t2 + 1][2] - m);
      float p7 = __builtin_amdgcn_exp2f(accs[2 * t2 + 1][3] - m);
      rs += ((p0 + p1) + (p2 + p3)) + ((p4 + p5) + (p6 + p7));
      union { unsigned u[4]; short8 v; } pu;
      pu.u[0] = cvtpk_bf16(p0, p1);
      pu.u[1] = cvtpk_bf16(p2, p3);
      pu.u[2] = cvtpk_bf16(p4, p5);
      pu.u[3] = cvtpk_bf16(p6, p7);
      pk8[t2] = pu.v;
    }
    l += rs;

    __builtin_amdgcn_s_setprio(1);
#pragma unroll
    for (int dt = 0; dt < 4; ++dt) {
      int rb = (dt * 16 + l15) * 64;
#pragma unroll
      for (int t2 = 0; t2 < 2; ++t2) {
        union { short4v hh[2]; short8 v; } vu;
        vu.hh[0] = *(const short4v*)&Vc[rb + voff[2 * t2]];
        vu.hh[1] = *(const short4v*)&Vc[rb + voff[2 * t2 + 1]];
        acc_o[dt] = __builtin_amdgcn_mfma_f32_16x16x32_bf16(vu.v, pk8[t2], acc_o[dt], 0, 0, 0);
      }
    }
    __builtin_amdgcn_s_setprio(0);

    if (more) {
      *(short8*)&Ks[cur ^ 1][wo] = nk;
      *(short8*)&Vs[cur ^ 1][wo] = nv;
      if (it + 2 <= last) {
        int kv2 = kv0 + 128;
        nk = *(const short8*)&kh[(size_t)(kv2 + sr) * DHEAD + scc];
        nv = *(const short8*)&vh[(size_t)sr * S_LEN + kv2 + scc];
      }
    }
    __syncthreads();
    cur ^= 1;
  }

  l += __shfl_xor(l, 16);
  l += __shfl_xor(l, 32);
  float rl = (l > 0.f) ? 1.f / l : 0.f;
#pragma unroll
  for (int dt = 0; dt < 4; ++dt) {
    ushort4 o;
    o.x = f2bf(acc_o[dt][0] * rl);
    o.y = f2bf(acc_o[dt][1] * rl);
    o.z = f2bf(acc_o[dt][2] * rl);
    o.w = f2bf(acc_o[dt][3] * rl);
    *(ushort4*)&O[(size_t)qrow * D_EMB + h * DHEAD + dt * 16 + g * 4] = o;
  }
}

extern "C" void kernel_launch(void* const* d_in, const int* in_sizes, int n_in,
                              void* d_out, int out_size, void* d_ws, size_t ws_size,
                              hipStream_t stream) {
  const float* x = (const float*)d_in[0];
  const float* W_in = (const float*)d_in[1];
  const float* b_in = (const float*)d_in[2];
  const float* W_out = (const float*)d_in[3];
  const float* b_out = (const float*)d_in[4];
  float* out = (float*)d_out;
  ushort* ws = (ushort*)d_ws;

  prep_kernel<<<8192, 256, 0, stream>>>(x, W_in, W_out,
                                        ws + OFF_XB, ws + OFF_WINT, ws + OFF_WOUTT);
  gemm1_8phase<<<dim3(12, 16), 512, 0, stream>>>(
      ws + OFF_XB, ws + OFF_WINT, b_in, ws + OFF_Q);
  attn_kernel<<<512, 512, 0, stream>>>(
      ws + OFF_Q, ws + OFF_Q + 4194304u, ws + OFF_Q + 8388608u, ws + OFF_ATTN);
  gemm2_kernel<<<dim3(16, 32), 256, 0, stream>>>(
      ws + OFF_ATTN, ws + OFF_WOUTT, b_out, out, D_EMB, D_EMB);
}